// Round 1
// baseline (158.033 us; speedup 1.0000x reference)
//
#include <hip/hip_runtime.h>
#include <cstdint>
#include <cstddef>

// ---------------------------------------------------------------------------
// DeMash = complex GEMM: out[bts, m] = sum_l y[bts, l] * conj(C)[m, l]
//   out_r = Yr@Cr^T + Yi@Ci^T ; out_i = Yi@Cr^T - Yr@Ci^T
// One real NT GEMM:
//   A [M=2048, K=3072] row-major fp16  (K: [Yr(1512) | Yi(1512) | 0-pad])
//   W [N=3072, K=3072] row-major fp16  (n<1512: [Cr|Ci|0]; 1512..3023:
//                                       [-Ci|Cr|0]; rest 0)
//   Out[m, n] = sum_k A[m,k] * W[n,k] -> scattered into [2,2048,14,128]
//
// R8: BK 64 -> 128 (single-buffered, 48 KB LDS). Rocprof showed MfmaUtil 26%,
// VALUBusy 17%, HBM 19% -> ~57% of gemm time is the per-K-step
// vmcnt(0)+barrier drain (m233-style 2-phase stall). Halving the K-step
// count (48 -> 24) amortizes each drain over 2x MFMA while KEEPING
// 3 blocks/CU (3 x 48 KB = 144 <= 160 KB LDS) -- the occupancy loss that
// killed BK=128 in other contexts does not apply at this tile.
// Swizzle re-derived for 16 chunks/row: stage g = slot ^ (row & 15),
// read slot = chunk ^ fr; each 8-lane b128 group hits 8 distinct 16B slots.
// prep_all unchanged (R7 coalesced version).
// ---------------------------------------------------------------------------

typedef _Float16 half_t;
typedef half_t half8 __attribute__((ext_vector_type(8)));
typedef half_t half4 __attribute__((ext_vector_type(4)));
typedef half_t half2_t __attribute__((ext_vector_type(2)));
typedef float floatx4 __attribute__((ext_vector_type(4)));
typedef float floatv4 __attribute__((ext_vector_type(4)));

#define M_DIM 2048
#define N_DIM 3072
#define K_DIM 3072
#define LDIM 1512
#define NSC 108
#define SYMS 14
#define FFT 128
#define ROWLEN (SYMS * FFT)   // 1792

#define BM 64
#define BN 128
#define BK 128
#define NITER (K_DIM / BK)    // 24

// prep grid partition (blocks of 256 threads)
#define PA2_BLOCKS 6048   // A: 2048 rows x 14 syms x 54 j-pairs / 256
#define PW2_BLOCKS 9072   // W: 3072 rows x 756 k-quads / 256
#define PAP_BLOCKS 48     // A k-pad zero: 2048 x 48 halves / 8 / 256
#define PG_BLOCKS 4480    // guard zero: 2*2048*14*20 / 256
#define PREP_BLOCKS (PA2_BLOCKS + PW2_BLOCKS + PAP_BLOCKS + PG_BLOCKS)

typedef __attribute__((address_space(3))) uint32_t lds_u32_t;
typedef const __attribute__((address_space(1))) uint32_t glob_u32_t;

__device__ __forceinline__ void gl2lds16(const void* g, void* l) {
    __builtin_amdgcn_global_load_lds((glob_u32_t*)g, (lds_u32_t*)l, 16, 0, 0);
}

// ---------------------------------------------------------------------------
// prep_all (one dispatch, 4 regions, wave-uniform region branch):
//  [0, PA2): A-build. thread -> (row, sym, jp); lanes walk jp so loads of
//            xr/xi are 8B-stride coalesced, stores are contiguous half2.
//  [PA2, +PW2): W-build. thread -> (n, kq): one float4 load (contiguous
//            across lanes), half4 store. Rows >= 3024 write zeros.
//  then A k-pad zeros (cols 3024..3071), then output guard-column zeros.
// ---------------------------------------------------------------------------
__global__ __launch_bounds__(256) void prep_all(
    const float* __restrict__ xr, const float* __restrict__ xi,
    const float* __restrict__ Cr, const float* __restrict__ Ci,
    const int* __restrict__ sc,
    half_t* __restrict__ A, half_t* __restrict__ W, float* __restrict__ out)
{
    const int b = blockIdx.x;
    const int t = threadIdx.x;

    if (b < PA2_BLOCKS) {
        int idx = b * 256 + t;          // [0, 2048*14*54)
        int jp = idx % 54;
        int rest = idx / 54;
        int sym = rest % 14;
        int row = rest / 14;
        int s0 = sc[2 * jp];
        int s1 = sc[2 * jp + 1];
        const float* xrp = xr + (size_t)row * ROWLEN + sym * FFT;
        const float* xip = xi + (size_t)row * ROWLEN + sym * FFT;
        half2_t hr = { (half_t)xrp[s0], (half_t)xrp[s1] };
        half2_t hi = { (half_t)xip[s0], (half_t)xip[s1] };
        size_t dst = (size_t)row * K_DIM + sym * NSC + 2 * jp;
        *(half2_t*)(A + dst) = hr;
        *(half2_t*)(A + dst + LDIM) = hi;
    } else if (b < PA2_BLOCKS + PW2_BLOCKS) {
        int idx = (b - PA2_BLOCKS) * 256 + t;   // [0, 3072*756)
        int kq = idx % 756;
        int n = idx / 756;
        int k0 = kq * 4;
        floatv4 f = {0.0f, 0.0f, 0.0f, 0.0f};
        if (n < LDIM) {
            if (k0 < LDIM)
                f = *(const floatv4*)(Cr + (size_t)n * LDIM + k0);
            else
                f = *(const floatv4*)(Ci + (size_t)n * LDIM + (k0 - LDIM));
        } else if (n < 2 * LDIM) {
            int m = n - LDIM;
            if (k0 < LDIM) {
                f = *(const floatv4*)(Ci + (size_t)m * LDIM + k0);
                f = -f;
            } else {
                f = *(const floatv4*)(Cr + (size_t)m * LDIM + (k0 - LDIM));
            }
        }
        half4 h = { (half_t)f.x, (half_t)f.y, (half_t)f.z, (half_t)f.w };
        *(half4*)(W + (size_t)n * K_DIM + k0) = h;
    } else if (b < PA2_BLOCKS + PW2_BLOCKS + PAP_BLOCKS) {
        int idx = (b - PA2_BLOCKS - PW2_BLOCKS) * 256 + t;  // [0, 12288)
        int c = idx % 6;
        int row = idx / 6;
        half8 z = {};
        *(half8*)(A + (size_t)row * K_DIM + 2 * LDIM + c * 8) = z;
    } else {
        // zero guard columns [0,10) U [118,128) for all 4096 rows x 14 syms
        int idx = (b - PA2_BLOCKS - PW2_BLOCKS - PAP_BLOCKS) * 256 + t;
        int c20 = idx % 20;
        int rest = idx / 20;
        int sym = rest % 14;
        int rowri = rest / 14;                 // [0, 4096) covers both ri
        int col = (c20 < 10) ? c20 : (NSC + c20);
        out[(size_t)rowri * ROWLEN + sym * FFT + col] = 0.0f;
    }
}

// ---------------------------------------------------------------------------
// gemm_scatter: 64x128 tile, BK=128, single-buffered (48 KB LDS),
// 4 waves each 64Mx32N via 4x2 mfma_f32_16x16x32_f16 x 4 k-steps.
// grid (24, 32) = 768 blocks = 3/CU (LDS: 3 x 48 KB = 144 <= 160 KB).
// 24 K-iterations -> 24 vmcnt-drain+barrier events (was 48).
// XOR bank swizzle across 16 chunks/row (conflict-free b128 reads).
// ---------------------------------------------------------------------------
__global__ __launch_bounds__(256) void gemm_scatter(
    const half_t* __restrict__ A,   // [M_DIM][K_DIM]
    const half_t* __restrict__ W,   // [N_DIM][K_DIM]
    const int* __restrict__ sc,
    float* __restrict__ out)        // [2][2048][14][128]; guards pre-zeroed
{
    __shared__ __align__(16) half_t As[BM * BK];   // 16 KB
    __shared__ __align__(16) half_t Bs[BN * BK];   // 32 KB

    const int t = threadIdx.x;
    const int bn = blockIdx.x;
    const int bm = blockIdx.y;
    const int lane = t & 63;
    const int wn = (t >> 6) * 32;     // wave's N offset in tile

    floatx4 acc[4][2] = {};

    // staging: chunk c (16B): row = c>>4, slot = c&15, global k-chunk
    // g = slot ^ (row&15). LDS dest = base + c*16 (contiguous per lane).
    const half_t* gAp[4];
    const half_t* gBp[8];
    half_t* lAp[4];
    half_t* lBp[8];
#pragma unroll
    for (int r = 0; r < 4; ++r) {
        int c = r * 256 + t;
        int row = c >> 4, slot = c & 15;
        int g = slot ^ (row & 15);
        gAp[r] = A + (size_t)(bm * BM + row) * K_DIM + g * 8;
        lAp[r] = As + c * 8;
    }
#pragma unroll
    for (int r = 0; r < 8; ++r) {
        int c = r * 256 + t;
        int row = c >> 4, slot = c & 15;
        int g = slot ^ (row & 15);
        gBp[r] = W + (size_t)(bn * BN + row) * K_DIM + g * 8;
        lBp[r] = Bs + c * 8;
    }

    const int fr = lane & 15;         // fragment row (M or N within 16)
    const int cr = lane >> 4;         // k-quad index within a 32-k step

    for (int kb = 0; kb < NITER; ++kb) {
        __syncthreads();
#pragma unroll
        for (int r = 0; r < 4; ++r) gl2lds16(gAp[r], lAp[r]);
#pragma unroll
        for (int r = 0; r < 8; ++r) gl2lds16(gBp[r], lBp[r]);
#pragma unroll
        for (int r = 0; r < 4; ++r) gAp[r] += BK;
#pragma unroll
        for (int r = 0; r < 8; ++r) gBp[r] += BK;
        __syncthreads();

        // process the 128-k tile as two 64-k halves (keeps frag regs low)
#pragma unroll
        for (int h = 0; h < 2; ++h) {
            half8 af[2][4], bf[2][2];
#pragma unroll
            for (int ss = 0; ss < 2; ++ss) {
                // global chunk (h*8 + ss*4 + cr) lives at LDS slot ^ fr
                int slot = ((h << 3) | (ss << 2) | cr) ^ fr;
#pragma unroll
                for (int i = 0; i < 4; ++i)
                    af[ss][i] = *(const half8*)&As[(i * 16 + fr) * BK + slot * 8];
#pragma unroll
                for (int j = 0; j < 2; ++j)
                    bf[ss][j] = *(const half8*)&Bs[(wn + j * 16 + fr) * BK + slot * 8];
            }
#pragma unroll
            for (int ss = 0; ss < 2; ++ss)
#pragma unroll
                for (int i = 0; i < 4; ++i)
#pragma unroll
                    for (int j = 0; j < 2; ++j)
                        acc[i][j] = __builtin_amdgcn_mfma_f32_16x16x32_f16(
                            af[ss][i], bf[ss][j], acc[i][j], 0, 0, 0);
        }
    }

    // epilogue: C/D layout col = lane&15 (N), row = (lane>>4)*4 + reg (M)
    const int col_base = bn * BN + wn + (lane & 15);
    const int row_base = bm * BM + ((lane >> 4) * 4);
#pragma unroll
    for (int j = 0; j < 2; ++j) {
        int n = col_base + j * 16;
        if (n >= 2 * LDIM) continue;           // N-pad region: discard
        int ri = (n >= LDIM) ? 1 : 0;
        int nn = n - ri * LDIM;
        int sym = nn / NSC;
        int jj = nn - sym * NSC;
        size_t colOff = (size_t)ri * (M_DIM * ROWLEN) + sym * FFT + sc[jj];
#pragma unroll
        for (int i = 0; i < 4; ++i) {
            int row0 = row_base + i * 16;
#pragma unroll
            for (int r = 0; r < 4; ++r) {
                out[colOff + (size_t)(row0 + r) * ROWLEN] = acc[i][j][r];
            }
        }
    }
}

// ---------------------------------------------------------------------------
extern "C" void kernel_launch(void* const* d_in, const int* in_sizes, int n_in,
                              void* d_out, int out_size, void* d_ws, size_t ws_size,
                              hipStream_t stream) {
    const float* xr = (const float*)d_in[0];
    const float* xi = (const float*)d_in[1];
    const float* Cr = (const float*)d_in[2];
    const float* Ci = (const float*)d_in[3];
    const int* sc   = (const int*)d_in[4];
    float* out = (float*)d_out;

    half_t* Ah = (half_t*)d_ws;                                      // 12.58 MB
    half_t* Wh = (half_t*)((char*)d_ws + (size_t)M_DIM * K_DIM * 2); // 18.87 MB

    prep_all<<<PREP_BLOCKS, 256, 0, stream>>>(
        xr, xi, Cr, Ci, sc, Ah, Wh, out);

    dim3 grid(N_DIM / BN, M_DIM / BM);   // (24, 32) = 768 blocks
    gemm_scatter<<<grid, 256, 0, stream>>>(Ah, Wh, sc, out);
}

// Round 2
// 144.665 us; speedup vs baseline: 1.0924x; 1.0924x over previous
//
#include <hip/hip_runtime.h>
#include <cstdint>
#include <cstddef>

// ---------------------------------------------------------------------------
// DeMash = complex GEMM: out[bts, m] = sum_l y[bts, l] * conj(C)[m, l]
//   out_r = Yr@Cr^T + Yi@Ci^T ; out_i = Yi@Cr^T - Yr@Ci^T
//
// R9: explicit COMPLEX gemm (was: one real NT GEMM with duplicated
// [Cr|Ci;-Ci|Cr] W). R8 post-mortem: kernel is LDS-port-bound (frag
// ds_reads 1.81 GB + staging writes 906 MB ~= 46 us of port time at
// measured b128 rates = 80% of the 57.7 us kernel; MfmaUtil 27% = exact
// MFMA floor). Complex pairing makes every staged fragment feed TWO
// mfmas (out_r and out_i products):
//   A2 [2048][3072] fp16 : [Yr(1536, zero-padded from 1512) | Yi(1536)]
//   W2 [1536][3072] fp16 : [Cr(1536) | Ci(1536)]  (9.4 MB, half of old W)
//   block: 64M x 64N' tile of BOTH out_r/out_i; 4 accs RR,II,IR,RI;
//   epilogue r = RR+II, i = IR-RI (no in-loop negation).
// ds_read traffic 1.81 -> 1.21 GB; staging 906 -> 604 MB.
// Grid stays 768 blocks = 3/CU, 256 thr, single-buffer 2-barrier, same
// proven XOR chunk swizzle (conflicts were 0). LDS 32 KB/block.
// ---------------------------------------------------------------------------

typedef _Float16 half_t;
typedef half_t half8 __attribute__((ext_vector_type(8)));
typedef half_t half4 __attribute__((ext_vector_type(4)));
typedef half_t half2_t __attribute__((ext_vector_type(2)));
typedef float floatx4 __attribute__((ext_vector_type(4)));
typedef float floatv4 __attribute__((ext_vector_type(4)));

#define M_DIM 2048
#define K_DIM 3072            // [Yr 1536 | Yi 1536]
#define L_PAD 1536            // 1512 padded to 24*64
#define N2_DIM 1536           // W2 rows (n' padded)
#define LDIM 1512
#define NSC 108
#define SYMS 14
#define FFT 128
#define ROWLEN (SYMS * FFT)   // 1792

#define BM 64
#define BN 64                 // N' tile (complex columns)
#define BK 64                 // l-step per iteration
#define NITER (L_PAD / BK)    // 24

// prep grid partition (blocks of 256 threads)
#define PA2_BLOCKS 6048   // A: 2048 rows x 14 syms x 54 j-pairs / 256
#define PW2_BLOCKS 4608   // W2: 1536 rows x 768 k-quads / 256
#define PAP_BLOCKS 48     // A pad zero: 2048 x 48 halves / 8 / 256
#define PG_BLOCKS 4480    // guard zero: 2*2048*14*20 / 256
#define PREP_BLOCKS (PA2_BLOCKS + PW2_BLOCKS + PAP_BLOCKS + PG_BLOCKS)

typedef __attribute__((address_space(3))) uint32_t lds_u32_t;
typedef const __attribute__((address_space(1))) uint32_t glob_u32_t;

__device__ __forceinline__ void gl2lds16(const void* g, void* l) {
    __builtin_amdgcn_global_load_lds((glob_u32_t*)g, (lds_u32_t*)l, 16, 0, 0);
}

// ---------------------------------------------------------------------------
// prep_all (one dispatch, 4 regions, wave-uniform region branch):
//  [0, PA2): A-build. Yr at col sym*108+2jp, Yi at +1536.
//  [PA2, +PW2): W2-build. row n'<1536: cols [0,1536)=Cr[n'], [1536,3072)=Ci.
//            zero when n'>=1512 or l>=1512. float4 load, half4 store.
//  then A pad zeros (cols 1512..1535 and 3048..3071), then guard zeros.
// ---------------------------------------------------------------------------
__global__ __launch_bounds__(256) void prep_all(
    const float* __restrict__ xr, const float* __restrict__ xi,
    const float* __restrict__ Cr, const float* __restrict__ Ci,
    const int* __restrict__ sc,
    half_t* __restrict__ A, half_t* __restrict__ W, float* __restrict__ out)
{
    const int b = blockIdx.x;
    const int t = threadIdx.x;

    if (b < PA2_BLOCKS) {
        int idx = b * 256 + t;          // [0, 2048*14*54)
        int jp = idx % 54;
        int rest = idx / 54;
        int sym = rest % 14;
        int row = rest / 14;
        int s0 = sc[2 * jp];
        int s1 = sc[2 * jp + 1];
        const float* xrp = xr + (size_t)row * ROWLEN + sym * FFT;
        const float* xip = xi + (size_t)row * ROWLEN + sym * FFT;
        half2_t hr = { (half_t)xrp[s0], (half_t)xrp[s1] };
        half2_t hi = { (half_t)xip[s0], (half_t)xip[s1] };
        size_t dst = (size_t)row * K_DIM + sym * NSC + 2 * jp;
        *(half2_t*)(A + dst) = hr;
        *(half2_t*)(A + dst + L_PAD) = hi;
    } else if (b < PA2_BLOCKS + PW2_BLOCKS) {
        int idx = (b - PA2_BLOCKS) * 256 + t;   // [0, 1536*768)
        int kq = idx % 768;
        int n = idx / 768;
        int k0 = kq * 4;
        floatv4 f = {0.0f, 0.0f, 0.0f, 0.0f};
        if (n < LDIM) {
            if (k0 < L_PAD) {
                if (k0 < LDIM)
                    f = *(const floatv4*)(Cr + (size_t)n * LDIM + k0);
            } else {
                int l = k0 - L_PAD;
                if (l < LDIM)
                    f = *(const floatv4*)(Ci + (size_t)n * LDIM + l);
            }
        }
        half4 h = { (half_t)f.x, (half_t)f.y, (half_t)f.z, (half_t)f.w };
        *(half4*)(W + (size_t)n * K_DIM + k0) = h;
    } else if (b < PA2_BLOCKS + PW2_BLOCKS + PAP_BLOCKS) {
        int idx = (b - PA2_BLOCKS - PW2_BLOCKS) * 256 + t;  // [0, 12288)
        int c = idx % 6;
        int row = idx / 6;
        int col = (c < 3) ? (LDIM + c * 8) : (L_PAD + LDIM + (c - 3) * 8);
        half8 z = {};
        *(half8*)(A + (size_t)row * K_DIM + col) = z;
    } else {
        // zero guard columns [0,10) U [118,128) for all 4096 rows x 14 syms
        int idx = (b - PA2_BLOCKS - PW2_BLOCKS - PAP_BLOCKS) * 256 + t;
        int c20 = idx % 20;
        int rest = idx / 20;
        int sym = rest % 14;
        int rowri = rest / 14;                 // [0, 4096) covers both ri
        int col = (c20 < 10) ? c20 : (NSC + c20);
        out[(size_t)rowri * ROWLEN + sym * FFT + col] = 0.0f;
    }
}

// ---------------------------------------------------------------------------
// gemm_scatter: complex 64x64 tile. 4 waves in 2x2 grid, each 32Mx32N'
// computing BOTH out_r and out_i (4 products RR,II,IR,RI via 2x2
// mfma_f32_16x16x32_f16 each). Every staged fragment feeds 2 mfmas.
// LDS: As[64][128] = [Yr-chunk | Yi-chunk], Ws[64][128] = [Cr | Ci].
// grid (24, 32) = 768 blocks = 3/CU (96 KB LDS). XOR chunk swizzle:
// stage chunk g at slot g^(row&15); read chunk q at slot q^fr.
// ---------------------------------------------------------------------------
__global__ __launch_bounds__(256, 3) void gemm_scatter(
    const half_t* __restrict__ A,   // [M_DIM][K_DIM]  [Yr|Yi]
    const half_t* __restrict__ W,   // [N2_DIM][K_DIM] [Cr|Ci]
    const int* __restrict__ sc,
    float* __restrict__ out)        // [2][2048][14][128]; guards pre-zeroed
{
    __shared__ __align__(16) half_t As[BM * 2 * BK];   // 16 KB
    __shared__ __align__(16) half_t Ws[BN * 2 * BK];   // 16 KB

    const int t = threadIdx.x;
    const int bn = blockIdx.x;
    const int bm = blockIdx.y;
    const int lane = t & 63;
    const int w = t >> 6;
    const int wm = (w >> 1) * 32;     // wave M offset in tile
    const int wn = (w & 1) * 32;      // wave N' offset in tile

    floatx4 aRR[2][2] = {}, aII[2][2] = {}, aIR[2][2] = {}, aRI[2][2] = {};

    // staging: chunk c (16B): row = c>>4, slot = c&15, global chunk
    // g = slot ^ (row&15); g<8 -> Yr/Cr col g*8, g>=8 -> Yi/Ci col
    // 1536+(g-8)*8. LDS dest = base + c*16 (contiguous per lane).
    const half_t* gA[4];
    const half_t* gW[4];
    half_t* lA[4];
    half_t* lW[4];
#pragma unroll
    for (int r = 0; r < 4; ++r) {
        int c = r * 256 + t;
        int row = c >> 4, slot = c & 15;
        int g = slot ^ (row & 15);
        int gcol = (g < 8) ? g * 8 : (L_PAD + (g - 8) * 8);
        gA[r] = A + (size_t)(bm * BM + row) * K_DIM + gcol;
        lA[r] = As + c * 8;
        gW[r] = W + (size_t)(bn * BN + row) * K_DIM + gcol;
        lW[r] = Ws + c * 8;
    }

    const int fr = lane & 15;         // fragment row (M or N' within 16)
    const int cr = lane >> 4;         // k-quad index within a 32-k step

    for (int kb = 0; kb < NITER; ++kb) {
        __syncthreads();
#pragma unroll
        for (int r = 0; r < 4; ++r) gl2lds16(gA[r], lA[r]);
#pragma unroll
        for (int r = 0; r < 4; ++r) gl2lds16(gW[r], lW[r]);
#pragma unroll
        for (int r = 0; r < 4; ++r) { gA[r] += BK; gW[r] += BK; }
        __syncthreads();

#pragma unroll
        for (int ss = 0; ss < 2; ++ss) {
            // Yr/Cr global chunk = ss*4+cr; Yi/Ci chunk = 8+ss*4+cr.
            const int sR = ((ss * 4 + cr) ^ fr) * 8;
            const int sI = ((8 + ss * 4 + cr) ^ fr) * 8;
            half8 yr[2], yi[2], cR[2], cI[2];
#pragma unroll
            for (int i = 0; i < 2; ++i) {
                int rb = (wm + i * 16 + fr) * (2 * BK);
                yr[i] = *(const half8*)&As[rb + sR];
                yi[i] = *(const half8*)&As[rb + sI];
            }
#pragma unroll
            for (int j = 0; j < 2; ++j) {
                int rb = (wn + j * 16 + fr) * (2 * BK);
                cR[j] = *(const half8*)&Ws[rb + sR];
                cI[j] = *(const half8*)&Ws[rb + sI];
            }
#pragma unroll
            for (int i = 0; i < 2; ++i)
#pragma unroll
                for (int j = 0; j < 2; ++j) {
                    aRR[i][j] = __builtin_amdgcn_mfma_f32_16x16x32_f16(
                        yr[i], cR[j], aRR[i][j], 0, 0, 0);
                    aII[i][j] = __builtin_amdgcn_mfma_f32_16x16x32_f16(
                        yi[i], cI[j], aII[i][j], 0, 0, 0);
                    aIR[i][j] = __builtin_amdgcn_mfma_f32_16x16x32_f16(
                        yi[i], cR[j], aIR[i][j], 0, 0, 0);
                    aRI[i][j] = __builtin_amdgcn_mfma_f32_16x16x32_f16(
                        yr[i], cI[j], aRI[i][j], 0, 0, 0);
                }
        }
    }

    // epilogue: C/D layout col = lane&15 (N'), row = (lane>>4)*4 + reg (M)
    const int rq = lane >> 4;
#pragma unroll
    for (int j = 0; j < 2; ++j) {
        int n = bn * BN + wn + j * 16 + fr;
        if (n >= LDIM) continue;               // N'-pad: discard
        int sym = n / NSC;
        int jj = n - sym * NSC;
        size_t colR = (size_t)sym * FFT + sc[jj];
        size_t colI = (size_t)M_DIM * ROWLEN + colR;
#pragma unroll
        for (int i = 0; i < 2; ++i) {
            int m0 = bm * BM + wm + i * 16 + rq * 4;
#pragma unroll
            for (int r = 0; r < 4; ++r) {
                float vr = aRR[i][j][r] + aII[i][j][r];
                float vi = aIR[i][j][r] - aRI[i][j][r];
                out[colR + (size_t)(m0 + r) * ROWLEN] = vr;
                out[colI + (size_t)(m0 + r) * ROWLEN] = vi;
            }
        }
    }
}

// ---------------------------------------------------------------------------
extern "C" void kernel_launch(void* const* d_in, const int* in_sizes, int n_in,
                              void* d_out, int out_size, void* d_ws, size_t ws_size,
                              hipStream_t stream) {
    const float* xr = (const float*)d_in[0];
    const float* xi = (const float*)d_in[1];
    const float* Cr = (const float*)d_in[2];
    const float* Ci = (const float*)d_in[3];
    const int* sc   = (const int*)d_in[4];
    float* out = (float*)d_out;

    half_t* Ah = (half_t*)d_ws;                                      // 12.58 MB
    half_t* Wh = (half_t*)((char*)d_ws + (size_t)M_DIM * K_DIM * 2); // 9.44 MB

    prep_all<<<PREP_BLOCKS, 256, 0, stream>>>(
        xr, xi, Cr, Ci, sc, Ah, Wh, out);

    dim3 grid(N2_DIM / BN, M_DIM / BM);   // (24, 32) = 768 blocks
    gemm_scatter<<<grid, 256, 0, stream>>>(Ah, Wh, sc, out);
}